// Round 3
// baseline (92.615 us; speedup 1.0000x reference)
//
#include <hip/hip_runtime.h>

// SpikeLayer: per-pixel CDF over C=128 channels + S=128 searchsorted lookups.
// B=64, C=128, H=64, W=64, S=128. Output int32 channel indices [B,S,H,W].
//
// R3: occupancy push. 32 pixels/block (8 groups x 16 channels), LDS 17.9 KB
// -> 8 blocks/CU = 32 waves/CU cap (was 4 blocks/16 waves). launch_bounds
// (256,8) to keep VGPR <= 64. Search: 4 register-cached levels + 2x
// ds_read_b128 final window (unchanged from R2).

#define BB 64
#define CC 128
#define HH 64
#define WW 64
#define SS 128

constexpr int PAD    = 132;          // floats per pixel row (528 B, 16B-aligned)
constexpr int PIX    = 32;           // pixels per block
constexpr int GROUPS = 8;            // thread groups (channel & spike split)
constexpr int KPG    = CC / GROUPS;  // 16 channels per group
constexpr int SPG    = SS / GROUPS;  // 16 spikes per group

__global__ __launch_bounds__(256, 8) void spike_kernel(
    const float* __restrict__ inp,   // [B,C,H,W]
    const float* __restrict__ rnd,   // [B,S,H,W]
    int* __restrict__ out) {         // [B,S,H,W]
  __shared__ float cdf[PIX * PAD];        // 32*132*4 = 16896 B
  __shared__ float gtot[GROUPS * PIX];    // 1024 B

  const int t = threadIdx.x;
  const int p = t & 31;     // pixel within block
  const int g = t >> 5;     // group (0..7)
  const int bid = blockIdx.x;
  const int b    = bid >> 7;          // / (HH*2)
  const int rem  = bid & 127;
  const int h    = rem >> 1;
  const int w0   = (rem & 1) << 5;    // 0 or 32
  const size_t HW = (size_t)HH * WW;
  const size_t pix_off = (size_t)h * WW + w0 + p;

  // ---- phase 1: per-group sequential cumsum, kept in registers ----
  const float* ip = inp + ((size_t)b * CC + g * KPG) * HW + pix_off;
  float vals[KPG];
  float run = 0.f;
#pragma unroll
  for (int k = 0; k < KPG; ++k) {
    run += ip[k * HW];
    vals[k] = run;
  }
  gtot[g * PIX + p] = run;
  __syncthreads();

  // ---- phase 2: cross-group prefix + vectorized CDF write ----
  float off = 0.f, total = 0.f;
#pragma unroll
  for (int gg = 0; gg < GROUPS; ++gg) {
    const float v = gtot[gg * PIX + p];
    total += v;
    if (gg < g) off += v;
  }

  float4* crow = (float4*)&cdf[p * PAD + g * KPG];
#pragma unroll
  for (int j = 0; j < KPG / 4; ++j) {
    float4 v;
    v.x = vals[4 * j + 0] + off;
    v.y = vals[4 * j + 1] + off;
    v.z = vals[4 * j + 2] + off;
    v.w = vals[4 * j + 3] + off;
    crow[j] = v;
  }
  __syncthreads();

  // ---- phase 3: register-cached top 4 levels, one LDS window per spike ----
  const int base = p * PAD;
  const float c63 = cdf[base + 63];
  const float c31 = cdf[base + 31], c95 = cdf[base + 95];
  const float c15 = cdf[base + 15], c47 = cdf[base + 47];
  const float c79 = cdf[base + 79], c111 = cdf[base + 111];
  const float c7  = cdf[base + 7],  c23 = cdf[base + 23];
  const float c39 = cdf[base + 39], c55 = cdf[base + 55];
  const float c71 = cdf[base + 71], c87 = cdf[base + 87];
  const float c103 = cdf[base + 103], c119 = cdf[base + 119];

  const float* rp = rnd + ((size_t)b * SS + g * SPG) * HW + pix_off;
  int*         op = out + ((size_t)b * SS + g * SPG) * HW + pix_off;

#pragma unroll 4
  for (int s = 0; s < SPG; ++s) {
    const float r = rp[s * HW] * total;
    const bool bl1 = c63 < r;
    const float v2 = bl1 ? c95 : c31;
    const bool bl2 = v2 < r;
    const float t3a = bl2 ? c47 : c15;
    const float t3b = bl2 ? c111 : c79;
    const float v3 = bl1 ? t3b : t3a;
    const bool bl3 = v3 < r;
    const float t4a = bl3 ? c23 : c7;
    const float t4b = bl3 ? c55 : c39;
    const float t4c = bl3 ? c87 : c71;
    const float t4d = bl3 ? c119 : c103;
    const float u4a = bl2 ? t4b : t4a;
    const float u4b = bl2 ? t4d : t4c;
    const float v4 = bl1 ? u4b : u4a;
    const bool bl4 = v4 < r;
    int idx = (bl1 ? 64 : 0) + (bl2 ? 32 : 0) + (bl3 ? 16 : 0) + (bl4 ? 8 : 0);
    const float4 ca = *(const float4*)&cdf[base + idx];
    const float4 cb = *(const float4*)&cdf[base + idx + 4];
    const int cnt = (ca.x < r) + (ca.y < r) + (ca.z < r) + (ca.w < r)
                  + (cb.x < r) + (cb.y < r) + (cb.z < r);
    op[s * HW] = idx + cnt;
  }
}

extern "C" void kernel_launch(void* const* d_in, const int* in_sizes, int n_in,
                              void* d_out, int out_size, void* d_ws, size_t ws_size,
                              hipStream_t stream) {
  const float* inp = (const float*)d_in[0];  // "input"         [B,C,H,W] f32
  const float* rnd = (const float*)d_in[1];  // "random_values" [B,S,H,W] f32
  int* out = (int*)d_out;                    // int32 indices   [B,S,H,W]
  (void)in_sizes; (void)n_in; (void)out_size; (void)d_ws; (void)ws_size;

  spike_kernel<<<dim3(BB * HH * 2), dim3(256), 0, stream>>>(inp, rnd, out);
}

// Round 4
// 67.442 us; speedup vs baseline: 1.3733x; 1.3733x over previous
//
#include <hip/hip_runtime.h>

// SpikeLayer: per-pixel CDF over C=128 channels + S=128 searchsorted lookups.
// B=64, C=128, H=64, W=64, S=128. Output int32 channel indices [B,S,H,W].
//
// R4: memory-level parallelism push. Explicitly batch all 16 phase-1 global
// loads and all 16 phase-3 rnd loads into register arrays so each phase pays
// ONE ~900cy HBM latency window instead of several register-recycled batches
// (R3 had VGPR_Count=28 -> compiler serialized the loads). Non-temporal
// stores on the output keep the 134MB write stream from evicting input/rnd
// from L3. Geometry unchanged from R3: 32 pix/block, 8 groups x 16ch,
// 17.9KB LDS, 8 blocks/CU.

#define BB 64
#define CC 128
#define HH 64
#define WW 64
#define SS 128

constexpr int PAD    = 132;          // floats per pixel row (528 B, 16B-aligned)
constexpr int PIX    = 32;           // pixels per block
constexpr int GROUPS = 8;            // thread groups (channel & spike split)
constexpr int KPG    = CC / GROUPS;  // 16 channels per group
constexpr int SPG    = SS / GROUPS;  // 16 spikes per group

__global__ __launch_bounds__(256, 8) void spike_kernel(
    const float* __restrict__ inp,   // [B,C,H,W]
    const float* __restrict__ rnd,   // [B,S,H,W]
    int* __restrict__ out) {         // [B,S,H,W]
  __shared__ float cdf[PIX * PAD];        // 32*132*4 = 16896 B
  __shared__ float gtot[GROUPS * PIX];    // 1024 B

  const int t = threadIdx.x;
  const int p = t & 31;     // pixel within block
  const int g = t >> 5;     // group (0..7)
  const int bid = blockIdx.x;
  const int b    = bid >> 7;          // / (HH*2)
  const int rem  = bid & 127;
  const int h    = rem >> 1;
  const int w0   = (rem & 1) << 5;    // 0 or 32
  const size_t HW = (size_t)HH * WW;
  const size_t pix_off = (size_t)h * WW + w0 + p;

  // ---- phase 1: batch-load 16 channels (all in flight), then cumsum ----
  const float* ip = inp + ((size_t)b * CC + g * KPG) * HW + pix_off;
  float x[KPG];
#pragma unroll
  for (int k = 0; k < KPG; ++k) x[k] = ip[k * HW];

  float vals[KPG];
  float run = 0.f;
#pragma unroll
  for (int k = 0; k < KPG; ++k) {
    run += x[k];
    vals[k] = run;
  }
  gtot[g * PIX + p] = run;
  __syncthreads();

  // ---- phase 2: cross-group prefix + vectorized CDF write ----
  float off = 0.f, total = 0.f;
#pragma unroll
  for (int gg = 0; gg < GROUPS; ++gg) {
    const float v = gtot[gg * PIX + p];
    total += v;
    if (gg < g) off += v;
  }

  float4* crow = (float4*)&cdf[p * PAD + g * KPG];
#pragma unroll
  for (int j = 0; j < KPG / 4; ++j) {
    float4 v;
    v.x = vals[4 * j + 0] + off;
    v.y = vals[4 * j + 1] + off;
    v.z = vals[4 * j + 2] + off;
    v.w = vals[4 * j + 3] + off;
    crow[j] = v;
  }
  __syncthreads();

  // ---- phase 3: batch-load all 16 rnd values, then search ----
  const float* rp = rnd + ((size_t)b * SS + g * SPG) * HW + pix_off;
  int*         op = out + ((size_t)b * SS + g * SPG) * HW + pix_off;

  float rv[SPG];
#pragma unroll
  for (int s = 0; s < SPG; ++s) rv[s] = rp[s * HW];

  const int base = p * PAD;
  const float c63 = cdf[base + 63];
  const float c31 = cdf[base + 31], c95 = cdf[base + 95];
  const float c15 = cdf[base + 15], c47 = cdf[base + 47];
  const float c79 = cdf[base + 79], c111 = cdf[base + 111];
  const float c7  = cdf[base + 7],  c23 = cdf[base + 23];
  const float c39 = cdf[base + 39], c55 = cdf[base + 55];
  const float c71 = cdf[base + 71], c87 = cdf[base + 87];
  const float c103 = cdf[base + 103], c119 = cdf[base + 119];

#pragma unroll
  for (int s = 0; s < SPG; ++s) {
    const float r = rv[s] * total;
    const bool bl1 = c63 < r;
    const float v2 = bl1 ? c95 : c31;
    const bool bl2 = v2 < r;
    const float t3a = bl2 ? c47 : c15;
    const float t3b = bl2 ? c111 : c79;
    const float v3 = bl1 ? t3b : t3a;
    const bool bl3 = v3 < r;
    const float t4a = bl3 ? c23 : c7;
    const float t4b = bl3 ? c55 : c39;
    const float t4c = bl3 ? c87 : c71;
    const float t4d = bl3 ? c119 : c103;
    const float u4a = bl2 ? t4b : t4a;
    const float u4b = bl2 ? t4d : t4c;
    const float v4 = bl1 ? u4b : u4a;
    const bool bl4 = v4 < r;
    int idx = (bl1 ? 64 : 0) + (bl2 ? 32 : 0) + (bl3 ? 16 : 0) + (bl4 ? 8 : 0);
    const float4 ca = *(const float4*)&cdf[base + idx];
    const float4 cb = *(const float4*)&cdf[base + idx + 4];
    const int cnt = (ca.x < r) + (ca.y < r) + (ca.z < r) + (ca.w < r)
                  + (cb.x < r) + (cb.y < r) + (cb.z < r);
    __builtin_nontemporal_store(idx + cnt, &op[s * HW]);
  }
}

extern "C" void kernel_launch(void* const* d_in, const int* in_sizes, int n_in,
                              void* d_out, int out_size, void* d_ws, size_t ws_size,
                              hipStream_t stream) {
  const float* inp = (const float*)d_in[0];  // "input"         [B,C,H,W] f32
  const float* rnd = (const float*)d_in[1];  // "random_values" [B,S,H,W] f32
  int* out = (int*)d_out;                    // int32 indices   [B,S,H,W]
  (void)in_sizes; (void)n_in; (void)out_size; (void)d_ws; (void)ws_size;

  spike_kernel<<<dim3(BB * HH * 2), dim3(256), 0, stream>>>(inp, rnd, out);
}